// Round 3
// baseline (504.115 us; speedup 1.0000x reference)
//
#include <hip/hip_runtime.h>

#define N_TOK 4096
#define DIM   1024
#define NEXP  8
#define FDIM  2048
#define CAP   2048

typedef __attribute__((ext_vector_type(8))) short short8;
typedef __attribute__((ext_vector_type(4))) float f32x4;

__device__ __forceinline__ unsigned short f2bf(float f) {
  union { float f; unsigned u; } v; v.f = f;
  unsigned r = v.u + 0x7fffu + ((v.u >> 16) & 1u);
  return (unsigned short)(r >> 16);
}

__device__ __forceinline__ void async_cp16(const void* g, void* l) {
  __builtin_amdgcn_global_load_lds((const __attribute__((address_space(1))) unsigned int*)g,
                                   (__attribute__((address_space(3))) unsigned int*)l,
                                   16, 0, 0);
}

__global__ void zero_counts_k(int* counts) {
  if (threadIdx.x < NEXP) counts[threadIdx.x] = 0;
}

// in: [E][R][C] fp32  ->  out: [E][C][R] bf16
__global__ void transpose_conv_k(const float* __restrict__ in, unsigned short* __restrict__ out,
                                 int R, int C) {
  __shared__ float tile[32][33];
  int tpc = C / 32, tpr = R / 32;
  int b = blockIdx.x;
  int e = b / (tpr * tpc);
  int rem = b % (tpr * tpc);
  int rt = rem / tpc, ct = rem % tpc;
  const float* inp = in + (size_t)e * R * C;
  unsigned short* outp = out + (size_t)e * R * C;
  int tx = threadIdx.x & 31, ty = threadIdx.x >> 5;  // ty in 0..7
  int r0 = rt * 32, c0 = ct * 32;
#pragma unroll
  for (int i = 0; i < 4; i++)
    tile[ty + 8 * i][tx] = inp[(size_t)(r0 + ty + 8 * i) * C + c0 + tx];
  __syncthreads();
#pragma unroll
  for (int i = 0; i < 4; i++)
    outp[(size_t)(c0 + ty + 8 * i) * R + r0 + tx] = f2bf(tile[tx][ty + 8 * i]);
}

__global__ void build_lists_k(const float* __restrict__ routing, int* counts,
                              int* idx, float* wgt) {
  int n = blockIdx.x * blockDim.x + threadIdx.x;
  if (n >= N_TOK) return;
  for (int e = 0; e < NEXP; e++) {
    float s = routing[(size_t)n * NEXP + e];
    if (s > 0.0f) {
      int pos = atomicAdd(&counts[e], 1);
      if (pos < CAP) { idx[e * CAP + pos] = n; wgt[e * CAP + pos] = s; }
    }
  }
}

// one block per (expert, slot): gather token row -> bf16, or zero-pad to 256-row tiles
__global__ void gather_pad_k(const float* __restrict__ x, const int* __restrict__ counts,
                             int* __restrict__ idx, float* __restrict__ wgt,
                             unsigned short* __restrict__ Xg) {
  int b = blockIdx.x;
  int e = b / CAP, i = b % CAP;
  int cnt = counts[e];
  int cntR = min((cnt + 255) & ~255, CAP);
  if (i >= cntR) return;
  int t = threadIdx.x;  // 0..255, 4 floats each
  unsigned short* row = Xg + (size_t)(e * CAP + i) * DIM;
  if (i < cnt) {
    int n = idx[e * CAP + i];
    const float4* xr = (const float4*)(x + (size_t)n * DIM);
    float4 v = xr[t];
    ushort4 o;
    o.x = f2bf(v.x); o.y = f2bf(v.y); o.z = f2bf(v.z); o.w = f2bf(v.w);
    ((ushort4*)row)[t] = o;
  } else {
    ((ushort4*)row)[t] = make_ushort4(0, 0, 0, 0);
    if (t == 0) { idx[e * CAP + i] = 0; wgt[e * CAP + i] = 0.0f; }
  }
}

// 256x128 tile, 8 waves (4M x 2N, per-wave 64x64 = 4x4 frags), BK=64.
// TRIPLE-buffered, counted vmcnt(6) + raw s_barrier: tile t computes from
// buf[t%3] while tile t+2 stages into buf[(t+2)%3]; at each boundary wait
// vmcnt(6) so the newest tile's 6 loads/wave stay in flight (never drain to 0).
// A: [E][CAP][KDIM] bf16 row-major. Bt: [E][NCOLS][KDIM] bf16 (B^T).
// EPI 0: H = gelu(A.B + b0) (bf16). EPI 1: atomicAdd(out[token], (A.B + b1)*wgt).
template <int EPI, int KDIM, int NCOLS>
__global__ __launch_bounds__(512, 2) void gemm_k(
    const unsigned short* __restrict__ A, const unsigned short* __restrict__ Bt,
    const float* __restrict__ bias, const int* __restrict__ counts,
    const int* __restrict__ idx, const float* __restrict__ wgt,
    unsigned short* __restrict__ Hout, float* __restrict__ out) {
  constexpr int BM = 256, BN = 128, BK = 64;
  constexpr int KT = KDIM / BK;
  constexpr int MT = CAP / BM;          // 8
  constexpr int NT = NCOLS / BN;        // 16 (gemm1) / 8 (gemm2)
  constexpr int BUFE = BM * BK + BN * BK;  // 24576 elems = 48KB
  __shared__ unsigned short lds[3 * BUFE]; // 144KB

  int nwg = NEXP * MT * NT;
  int b = blockIdx.x;
  b = (b & 7) * (nwg >> 3) + (b >> 3);   // bijective XCD swizzle (nwg % 8 == 0)
  int e = b / (MT * NT);
  int rem = b % (MT * NT);
  int mt = rem / NT, nt = rem % NT;
  int cnt = counts[e];
  int cntR = min((cnt + 255) & ~255, CAP);
  int m0 = mt * BM;
  if (m0 >= cntR) return;
  int n0 = nt * BN;

  const unsigned short* Ae = A + (size_t)e * CAP * KDIM;
  const unsigned short* Be = Bt + (size_t)e * NCOLS * KDIM;

  int tid = threadIdx.x;
  int lane = tid & 63;
  int w = tid >> 6;          // 0..7
  int wr = w & 3, wc = w >> 2;

  // staging: chunks of 1KB (8 rows x 64 cols); A = 32 chunks, B = 16 chunks.
  // lane l -> row chunk*8 + (l>>3), phys 16B slot (l&7); XOR-swizzle the GLOBAL
  // source so LDS lands pre-swizzled (linear dest + inv-swz src; conflicts = 0).
  int srow = lane >> 3;
  int scl = (lane & 7) ^ srow;

  auto stage = [&](int buf, int k0) {
    unsigned short* bp = &lds[buf * BUFE];
#pragma unroll
    for (int r = 0; r < 4; r++) {       // A: 4 loads/thread
      int ch = r * 8 + w;
      async_cp16(Ae + (size_t)(m0 + ch * 8 + srow) * KDIM + k0 + scl * 8, bp + ch * 512);
    }
#pragma unroll
    for (int r = 0; r < 2; r++) {       // B: 2 loads/thread
      int ch = r * 8 + w;
      async_cp16(Be + (size_t)(n0 + ch * 8 + srow) * KDIM + k0 + scl * 8,
                 bp + BM * BK + ch * 512);
    }
  };

  f32x4 acc[4][4];
#pragma unroll
  for (int m = 0; m < 4; m++)
#pragma unroll
    for (int n = 0; n < 4; n++) acc[m][n] = (f32x4){0.f, 0.f, 0.f, 0.f};

  // prologue: tiles 0,1 in flight; wait tile0 (6 newest = tile1 stay in flight)
  stage(0, 0);
  stage(1, BK);
  asm volatile("s_waitcnt vmcnt(6)\n\ts_barrier" ::: "memory");

  int ibc = 0, ibs = 2;
#pragma unroll 1
  for (int t = 0; t < KT; ++t) {
    if (t + 2 < KT) stage(ibs, (t + 2) * BK);
    const unsigned short* bp = &lds[ibc * BUFE];
    const unsigned short* bpB = bp + BM * BK;
    __builtin_amdgcn_s_setprio(1);
#pragma unroll
    for (int ks = 0; ks < 2; ks++) {
      short8 av[4], bv[4];
#pragma unroll
      for (int m = 0; m < 4; m++) {
        int r = wr * 64 + m * 16 + (lane & 15);
        int cp = (ks * 4 + (lane >> 4)) ^ (r & 7);
        av[m] = *(const short8*)&bp[r * 64 + cp * 8];
      }
#pragma unroll
      for (int n = 0; n < 4; n++) {
        int r = wc * 64 + n * 16 + (lane & 15);
        int cp = (ks * 4 + (lane >> 4)) ^ (r & 7);
        bv[n] = *(const short8*)&bpB[r * 64 + cp * 8];
      }
#pragma unroll
      for (int m = 0; m < 4; m++)
#pragma unroll
        for (int n = 0; n < 4; n++)
          acc[m][n] = __builtin_amdgcn_mfma_f32_16x16x32_bf16(av[m], bv[n], acc[m][n], 0, 0, 0);
    }
    __builtin_amdgcn_s_setprio(0);
    if (t + 1 < KT) {
      if (t + 2 < KT) asm volatile("s_waitcnt vmcnt(6)\n\ts_barrier" ::: "memory");
      else            asm volatile("s_waitcnt vmcnt(0)\n\ts_barrier" ::: "memory");
    }
    ibc = (ibc == 2) ? 0 : ibc + 1;
    ibs = (ibs == 2) ? 0 : ibs + 1;
  }

  // epilogue; C/D map: col = lane&15, row = (lane>>4)*4 + reg
  int lr = (lane >> 4) * 4;
  int lc = lane & 15;
#pragma unroll
  for (int n = 0; n < 4; n++) {
    int gc = n0 + wc * 64 + n * 16 + lc;
    float bb = bias[e * NCOLS + gc];
#pragma unroll
    for (int m = 0; m < 4; m++) {
      int gr = m0 + wr * 64 + m * 16 + lr;
      f32x4 v = acc[m][n];
#pragma unroll
      for (int r = 0; r < 4; r++) {
        int row = gr + r;
        float tv = v[r] + bb;
        if (EPI == 0) {
          float g = tv * 0.5f * (1.0f + erff(tv * 0.70710678118f));
          Hout[(size_t)(e * CAP + row) * NCOLS + gc] = f2bf(g);
        } else {
          int token = idx[e * CAP + row];
          float wv = wgt[e * CAP + row];
          atomicAdd(out + (size_t)token * NCOLS + gc, tv * wv);
        }
      }
    }
  }
}

extern "C" void kernel_launch(void* const* d_in, const int* in_sizes, int n_in,
                              void* d_out, int out_size, void* d_ws, size_t ws_size,
                              hipStream_t stream) {
  const float* x  = (const float*)d_in[0];
  const float* rt = (const float*)d_in[1];
  const float* w0 = (const float*)d_in[2];
  const float* b0 = (const float*)d_in[3];
  const float* w1 = (const float*)d_in[4];
  const float* b1 = (const float*)d_in[5];
  float* out = (float*)d_out;

  char* ws = (char*)d_ws;
  int* counts = (int*)ws;                              // 256 B reserved
  int* idx    = (int*)(ws + 256);                      // 64 KB
  float* wgt  = (float*)(ws + 256 + 65536);            // 64 KB
  unsigned short* w0T = (unsigned short*)(ws + 256 + 2 * 65536);
  unsigned short* w1T = w0T + (size_t)NEXP * DIM * FDIM;      // +33.5 MB
  unsigned short* Xg  = w1T + (size_t)NEXP * DIM * FDIM;      // +33.5 MB
  unsigned short* Hb  = Xg + (size_t)NEXP * CAP * DIM;        // +33.5 MB (H: 67 MB)

  hipMemsetAsync(d_out, 0, (size_t)N_TOK * DIM * sizeof(float), stream);
  zero_counts_k<<<1, 64, 0, stream>>>(counts);
  // w0 [E][D][F] -> w0T [E][F][D] bf16 ; w1 [E][F][D] -> w1T [E][D][F] bf16
  transpose_conv_k<<<NEXP * (DIM / 32) * (FDIM / 32), 256, 0, stream>>>(w0, w0T, DIM, FDIM);
  transpose_conv_k<<<NEXP * (FDIM / 32) * (DIM / 32), 256, 0, stream>>>(w1, w1T, FDIM, DIM);
  build_lists_k<<<N_TOK / 256, 256, 0, stream>>>(rt, counts, idx, wgt);
  gather_pad_k<<<NEXP * CAP, 256, 0, stream>>>(x, counts, idx, wgt, Xg);
  gemm_k<0, DIM, FDIM><<<NEXP * (CAP / 256) * (FDIM / 128), 512, 0, stream>>>(
      Xg, w0T, b0, counts, idx, wgt, Hb, nullptr);
  gemm_k<1, FDIM, DIM><<<NEXP * (CAP / 256) * (DIM / 128), 512, 0, stream>>>(
      Hb, w1T, b1, counts, idx, wgt, nullptr, out);
}

// Round 5
// 445.127 us; speedup vs baseline: 1.1325x; 1.1325x over previous
//
#include <hip/hip_runtime.h>

#define N_TOK 4096
#define DIM   1024
#define NEXP  8
#define FDIM  2048
#define CAP   2048

typedef __attribute__((ext_vector_type(8))) short short8;
typedef __attribute__((ext_vector_type(4))) float f32x4;

__device__ __forceinline__ unsigned short f2bf(float f) {
  union { float f; unsigned u; } v; v.f = f;
  unsigned r = v.u + 0x7fffu + ((v.u >> 16) & 1u);
  return (unsigned short)(r >> 16);
}

__device__ __forceinline__ void async_cp16(const void* g, void* l) {
  __builtin_amdgcn_global_load_lds((const __attribute__((address_space(1))) unsigned int*)g,
                                   (__attribute__((address_space(3))) unsigned int*)l,
                                   16, 0, 0);
}

__global__ void zero_counts_k(int* counts) {
  if (threadIdx.x < NEXP) counts[threadIdx.x] = 0;
}

// in: [E][R][C] fp32  ->  out: [E][C][R] bf16
__global__ void transpose_conv_k(const float* __restrict__ in, unsigned short* __restrict__ out,
                                 int R, int C) {
  __shared__ float tile[32][33];
  int tpc = C / 32, tpr = R / 32;
  int b = blockIdx.x;
  int e = b / (tpr * tpc);
  int rem = b % (tpr * tpc);
  int rt = rem / tpc, ct = rem % tpc;
  const float* inp = in + (size_t)e * R * C;
  unsigned short* outp = out + (size_t)e * R * C;
  int tx = threadIdx.x & 31, ty = threadIdx.x >> 5;  // ty in 0..7
  int r0 = rt * 32, c0 = ct * 32;
#pragma unroll
  for (int i = 0; i < 4; i++)
    tile[ty + 8 * i][tx] = inp[(size_t)(r0 + ty + 8 * i) * C + c0 + tx];
  __syncthreads();
#pragma unroll
  for (int i = 0; i < 4; i++)
    outp[(size_t)(c0 + ty + 8 * i) * R + r0 + tx] = f2bf(tile[tx][ty + 8 * i]);
}

__global__ void build_lists_k(const float* __restrict__ routing, int* counts,
                              int* idx, float* wgt) {
  int n = blockIdx.x * blockDim.x + threadIdx.x;
  if (n >= N_TOK) return;
  for (int e = 0; e < NEXP; e++) {
    float s = routing[(size_t)n * NEXP + e];
    if (s > 0.0f) {
      int pos = atomicAdd(&counts[e], 1);
      if (pos < CAP) { idx[e * CAP + pos] = n; wgt[e * CAP + pos] = s; }
    }
  }
}

// one block per (expert, slot): gather token row -> bf16, or zero-pad to 256-row tiles
__global__ void gather_pad_k(const float* __restrict__ x, const int* __restrict__ counts,
                             int* __restrict__ idx, float* __restrict__ wgt,
                             unsigned short* __restrict__ Xg) {
  int b = blockIdx.x;
  int e = b / CAP, i = b % CAP;
  int cnt = counts[e];
  int cntR = min((cnt + 255) & ~255, CAP);
  if (i >= cntR) return;
  int t = threadIdx.x;  // 0..255, 4 floats each
  unsigned short* row = Xg + (size_t)(e * CAP + i) * DIM;
  if (i < cnt) {
    int n = idx[e * CAP + i];
    const float4* xr = (const float4*)(x + (size_t)n * DIM);
    float4 v = xr[t];
    ushort4 o;
    o.x = f2bf(v.x); o.y = f2bf(v.y); o.z = f2bf(v.z); o.w = f2bf(v.w);
    ((ushort4*)row)[t] = o;
  } else {
    ((ushort4*)row)[t] = make_ushort4(0, 0, 0, 0);
    if (t == 0) { idx[e * CAP + i] = 0; wgt[e * CAP + i] = 0.0f; }
  }
}

// 256xBN tile, 8 waves (2M x 4N), per-wave 128 x BN/4 via 16x16x32 frags, BK=64.
// Simple double-buffered 2-phase: stage(next->other buf) -> compute(cur) -> syncthreads.
// Per-step MFMA (~2480cy for BN=256) covers the vmcnt(0) drain latency (~900cy).
// A: [E][CAP][KDIM] bf16 row-major. Bt: [E][NCOLS][KDIM] bf16 (B^T).
// EPI 0: H = gelu(A.B + b0) (bf16). EPI 1: atomicAdd(out[token], (A.B + b1)*wgt).
template <int EPI, int KDIM, int NCOLS, int BN>
__global__ __launch_bounds__(512, 2) void gemm_k(
    const unsigned short* __restrict__ A, const unsigned short* __restrict__ Bt,
    const float* __restrict__ bias, const int* __restrict__ counts,
    const int* __restrict__ idx, const float* __restrict__ wgt,
    unsigned short* __restrict__ Hout, float* __restrict__ out) {
  constexpr int BM = 256, BK = 64;
  constexpr int NREP = BN / 64;             // per-wave n-frags (4 or 2)
  constexpr int BLOADS = BN / 64;           // B-chunk loads per thread (BN/8 chunks / 8 waves)
  constexpr int KT = KDIM / BK;
  constexpr int MT = CAP / BM;              // 8
  constexpr int NT = NCOLS / BN;            // 8
  constexpr int AELEM = BM * BK;            // 16384
  constexpr int BUFE = AELEM + BN * BK;
  __shared__ unsigned short lds[2 * BUFE];  // 128KB (BN=256) / 96KB (BN=128)

  int nwg = NEXP * MT * NT;                 // 512
  int b = blockIdx.x;
  b = (b & 7) * (nwg >> 3) + (b >> 3);      // bijective XCD swizzle
  int e = b / (MT * NT);
  int rem = b % (MT * NT);
  int mt = rem / NT, nt = rem % NT;
  int cnt = counts[e];
  int cntR = min((cnt + 255) & ~255, CAP);
  int m0 = mt * BM;
  if (m0 >= cntR) return;
  int n0 = nt * BN;

  const unsigned short* Ae = A + (size_t)e * CAP * KDIM;
  const unsigned short* Be = Bt + (size_t)e * NCOLS * KDIM;

  int tid = threadIdx.x;
  int lane = tid & 63;
  int w = tid >> 6;           // 0..7
  int wm = w & 1, wn = w >> 1;

  // staging: 1KB chunks (8 rows x 64 cols); A = 32 chunks, B = BN/8 chunks.
  // lane l -> row chunk*8 + (l>>3), phys 16B slot ((l&7) ^ row&7) via
  // pre-swizzled GLOBAL source (linear LDS dest); measured 0 bank conflicts.
  int srow = lane >> 3;
  int scl = (lane & 7) ^ srow;

  auto stage = [&](int buf, int k0) {
    unsigned short* bp = &lds[buf * BUFE];
#pragma unroll
    for (int r = 0; r < 4; r++) {            // A: 4 loads/thread (32 chunks)
      int ch = r * 8 + w;
      async_cp16(Ae + (size_t)(m0 + ch * 8 + srow) * KDIM + k0 + scl * 8, bp + ch * 512);
    }
#pragma unroll
    for (int r = 0; r < BLOADS; r++) {       // B: BN/64 loads/thread
      int ch = r * 8 + w;
      async_cp16(Be + (size_t)(n0 + ch * 8 + srow) * KDIM + k0 + scl * 8,
                 bp + AELEM + ch * 512);
    }
  };

  f32x4 acc[8][NREP];
#pragma unroll
  for (int m = 0; m < 8; m++)
#pragma unroll
    for (int n = 0; n < NREP; n++) acc[m][n] = (f32x4){0.f, 0.f, 0.f, 0.f};

  auto compute = [&](int buf) {
    const unsigned short* bpA = &lds[buf * BUFE];
    const unsigned short* bpB = bpA + AELEM;
#pragma unroll
    for (int ks = 0; ks < 2; ks++) {
      short8 av[8], bv[NREP];
#pragma unroll
      for (int m = 0; m < 8; m++) {
        int r = wm * 128 + m * 16 + (lane & 15);
        int cp = (ks * 4 + (lane >> 4)) ^ (r & 7);
        av[m] = *(const short8*)&bpA[r * 64 + cp * 8];
      }
#pragma unroll
      for (int n = 0; n < NREP; n++) {
        int r = wn * (BN / 4) + n * 16 + (lane & 15);
        int cp = (ks * 4 + (lane >> 4)) ^ (r & 7);
        bv[n] = *(const short8*)&bpB[r * 64 + cp * 8];
      }
#pragma unroll
      for (int m = 0; m < 8; m++)
#pragma unroll
        for (int n = 0; n < NREP; n++)
          acc[m][n] = __builtin_amdgcn_mfma_f32_16x16x32_bf16(av[m], bv[n], acc[m][n], 0, 0, 0);
    }
  };

  stage(0, 0);
  __syncthreads();
#pragma unroll 1
  for (int t = 0; t < KT; ++t) {
    if (t + 1 < KT) stage((t + 1) & 1, (t + 1) * BK);  // prefetch overlaps compute
    compute(t & 1);
    __syncthreads();   // drains vmcnt(0): prefetch landed; reads of cur done
  }

  // epilogue; C/D map: col = lane&15, row = (lane>>4)*4 + reg
  int lr = (lane >> 4) * 4;
  int lc = lane & 15;
#pragma unroll
  for (int n = 0; n < NREP; n++) {
    int gc = n0 + wn * (BN / 4) + n * 16 + lc;
    float bb = bias[e * NCOLS + gc];
#pragma unroll
    for (int m = 0; m < 8; m++) {
      int gr = m0 + wm * 128 + m * 16 + lr;
      f32x4 v = acc[m][n];
#pragma unroll
      for (int r = 0; r < 4; r++) {
        int row = gr + r;
        float tv = v[r] + bb;
        if (EPI == 0) {
          float g = tv * 0.5f * (1.0f + erff(tv * 0.70710678118f));
          Hout[(size_t)(e * CAP + row) * NCOLS + gc] = f2bf(g);
        } else {
          int token = idx[e * CAP + row];
          float wv = wgt[e * CAP + row];
          atomicAdd(out + (size_t)token * NCOLS + gc, tv * wv);
        }
      }
    }
  }
}

extern "C" void kernel_launch(void* const* d_in, const int* in_sizes, int n_in,
                              void* d_out, int out_size, void* d_ws, size_t ws_size,
                              hipStream_t stream) {
  const float* x  = (const float*)d_in[0];
  const float* rt = (const float*)d_in[1];
  const float* w0 = (const float*)d_in[2];
  const float* b0 = (const float*)d_in[3];
  const float* w1 = (const float*)d_in[4];
  const float* b1 = (const float*)d_in[5];
  float* out = (float*)d_out;

  char* ws = (char*)d_ws;
  int* counts = (int*)ws;                              // 256 B reserved
  int* idx    = (int*)(ws + 256);                      // 64 KB
  float* wgt  = (float*)(ws + 256 + 65536);            // 64 KB
  unsigned short* w0T = (unsigned short*)(ws + 256 + 2 * 65536);
  unsigned short* w1T = w0T + (size_t)NEXP * DIM * FDIM;      // +33.5 MB
  unsigned short* Xg  = w1T + (size_t)NEXP * DIM * FDIM;      // +33.5 MB
  unsigned short* Hb  = Xg + (size_t)NEXP * CAP * DIM;        // +33.5 MB (H: 67 MB)

  hipMemsetAsync(d_out, 0, (size_t)N_TOK * DIM * sizeof(float), stream);
  zero_counts_k<<<1, 64, 0, stream>>>(counts);
  // w0 [E][D][F] -> w0T [E][F][D] bf16 ; w1 [E][F][D] -> w1T [E][D][F] bf16
  transpose_conv_k<<<NEXP * (DIM / 32) * (FDIM / 32), 256, 0, stream>>>(w0, w0T, DIM, FDIM);
  transpose_conv_k<<<NEXP * (FDIM / 32) * (DIM / 32), 256, 0, stream>>>(w1, w1T, FDIM, DIM);
  build_lists_k<<<N_TOK / 256, 256, 0, stream>>>(rt, counts, idx, wgt);
  gather_pad_k<<<NEXP * CAP, 256, 0, stream>>>(x, counts, idx, wgt, Xg);
  gemm_k<0, DIM, FDIM, 256><<<NEXP * (CAP / 256) * (FDIM / 256), 512, 0, stream>>>(
      Xg, w0T, b0, counts, idx, wgt, Hb, nullptr);
  gemm_k<1, FDIM, DIM, 128><<<NEXP * (CAP / 256) * (DIM / 128), 512, 0, stream>>>(
      Hb, w1T, b1, counts, idx, wgt, nullptr, out);
}